// Round 1
// baseline (37.274 us; speedup 1.0000x reference)
//
#include <hip/hip_runtime.h>
#include <math.h>

#define LQ 256
#define MEML 256
#define LK 512
#define BB 4
#define NH 8
#define DH 16
#define DM 128

// ---------------------------------------------------------------------------
// Projection: qs[row=i*4+b][o=h*16+d] = dot(h[i,b,:], Wq[o,:]) * paramR[h]
//             ks[row=j*4+b][o]        = dot(c[j,b,:], Wk[o,:]) * paramR[h]
// c = concat(mems, h). 8 rows per block, 128 threads (one per output o).
// ---------------------------------------------------------------------------
__global__ __launch_bounds__(128) void proj_kernel(
    const float* __restrict__ hh, const float* __restrict__ mems,
    const float* __restrict__ Wq, const float* __restrict__ Wk,
    const float* __restrict__ paramR,
    float* __restrict__ qs, float* __restrict__ ks)
{
    __shared__ float x[8 * 128];
    const int blk = blockIdx.x;
    const int t = threadIdx.x;
    const bool isQ = (blk < 128);                 // 128 q-blocks, 256 k-blocks
    const int row0 = isQ ? blk * 8 : (blk - 128) * 8;
    const float* __restrict__ W = isQ ? Wq : Wk;

    // stage 8 input rows (128 floats each) into LDS
    for (int r = 0; r < 8; ++r) {
        const int row = row0 + r;
        const float* src;
        if (isQ) {
            src = hh + row * DM;                  // row = i*4+b
        } else {
            const int j = row >> 2;
            src = (j < MEML) ? (mems + row * DM) : (hh + (row - MEML * BB) * DM);
        }
        x[r * 128 + t] = src[t];
    }
    __syncthreads();

    float acc[8] = {0, 0, 0, 0, 0, 0, 0, 0};
    const float* wrow = W + t * DM;
    for (int k = 0; k < DM; k += 4) {
        const float4 w = *(const float4*)(wrow + k);
        #pragma unroll
        for (int r = 0; r < 8; ++r) {
            acc[r] += x[r * 128 + k + 0] * w.x + x[r * 128 + k + 1] * w.y
                    + x[r * 128 + k + 2] * w.z + x[r * 128 + k + 3] * w.w;
        }
    }
    const float rs = paramR[t >> 4];
    float* dst = (isQ ? qs : ks) + row0 * 128 + t;
    #pragma unroll
    for (int r = 0; r < 8; ++r) dst[r * 128] = acc[r] * rs;
}

// ---------------------------------------------------------------------------
// Score: out[i][j][b][h] = | prod_d sin(u)/u |,  u = qs[i,b,h,d] - ks[j,b,h,d]
// Thread: bh = t&31 (b=bh>>3, h=bh&7), js = t>>5. Block: 2 i's x 64 j's.
// ---------------------------------------------------------------------------
__global__ __launch_bounds__(256) void score_kernel(
    const float* __restrict__ qs, const float* __restrict__ ks,
    float* __restrict__ out)
{
    const int t = threadIdx.x;
    const int bh = t & 31;
    const int js = t >> 5;                        // 0..7
    const int i0 = blockIdx.x * 2;                // 128 i-tiles
    const int jbase = blockIdx.y * 64;            // 8 j-tiles

    float q[2][16];
    #pragma unroll
    for (int ii = 0; ii < 2; ++ii) {
        const float* qp = qs + ((i0 + ii) * 32 + bh) * 16;
        #pragma unroll
        for (int d = 0; d < 16; d += 4) {
            const float4 v = *(const float4*)(qp + d);
            q[ii][d] = v.x; q[ii][d + 1] = v.y; q[ii][d + 2] = v.z; q[ii][d + 3] = v.w;
        }
    }

    for (int m = 0; m < 8; ++m) {
        const int j = jbase + m * 8 + js;
        float k[16];
        const float* kp = ks + (j * 32 + bh) * 16;
        #pragma unroll
        for (int d = 0; d < 16; d += 4) {
            const float4 v = *(const float4*)(kp + d);
            k[d] = v.x; k[d + 1] = v.y; k[d + 2] = v.z; k[d + 3] = v.w;
        }
        #pragma unroll
        for (int ii = 0; ii < 2; ++ii) {
            float prod = 1.0f;
            #pragma unroll
            for (int d = 0; d < 16; ++d) {
                const float u = q[ii][d] - k[d];
                const float s = (fabsf(u) < 1e-12f)
                                  ? 1.0f
                                  : __sinf(u) * __builtin_amdgcn_rcpf(u);
                prod *= s;
            }
            out[((i0 + ii) * LK + j) * 32 + bh] = fabsf(prod);
        }
    }
}

extern "C" void kernel_launch(void* const* d_in, const int* in_sizes, int n_in,
                              void* d_out, int out_size, void* d_ws, size_t ws_size,
                              hipStream_t stream) {
    const float* hh     = (const float*)d_in[0];
    const float* mems   = (const float*)d_in[1];
    const float* Wq     = (const float*)d_in[2];
    const float* Wk     = (const float*)d_in[3];
    const float* paramR = (const float*)d_in[4];
    float* out = (float*)d_out;

    float* qs = (float*)d_ws;                 // LQ*BB*128 = 131072 floats (512 KB)
    float* ks = qs + LQ * BB * DM;            // LK*BB*128 = 262144 floats (1 MB)

    proj_kernel<<<384, 128, 0, stream>>>(hh, mems, Wq, Wk, paramR, qs, ks);
    score_kernel<<<dim3(128, 8), 256, 0, stream>>>(qs, ks, out);
}

// Round 2
// 34.297 us; speedup vs baseline: 1.0868x; 1.0868x over previous
//
#include <hip/hip_runtime.h>
#include <math.h>

#define LQ 256
#define MEML 256
#define LK 512
#define BB 4
#define NH 8
#define DH 16
#define DM 128

constexpr float INV2PI = 0.15915494309189535f;

// ---------------------------------------------------------------------------
// Projection, pre-scaled by paramR[h]/(2*pi):
//   qs[row=i*4+b][o=h*16+d]  (row-major 128)
//   ksT[d4][j][bh=b*8+h] as float4  (coalesced k-loads in score kernel)
// ---------------------------------------------------------------------------
__global__ __launch_bounds__(128) void proj_kernel(
    const float* __restrict__ hh, const float* __restrict__ mems,
    const float* __restrict__ Wq, const float* __restrict__ Wk,
    const float* __restrict__ paramR,
    float* __restrict__ qs, float* __restrict__ ksT)
{
    __shared__ float x[8 * 128];
    const int blk = blockIdx.x;
    const int t = threadIdx.x;
    const bool isQ = (blk < 128);                 // 128 q-blocks, 256 k-blocks
    const int row0 = isQ ? blk * 8 : (blk - 128) * 8;
    const float* __restrict__ W = isQ ? Wq : Wk;

    for (int r = 0; r < 8; ++r) {
        const int row = row0 + r;
        const float* src;
        if (isQ) {
            src = hh + row * DM;
        } else {
            const int j = row >> 2;
            src = (j < MEML) ? (mems + row * DM) : (hh + (row - MEML * BB) * DM);
        }
        x[r * 128 + t] = src[t];
    }
    __syncthreads();

    float acc[8] = {0, 0, 0, 0, 0, 0, 0, 0};
    const float* wrow = W + t * DM;
    for (int k = 0; k < DM; k += 4) {
        const float4 w = *(const float4*)(wrow + k);
        #pragma unroll
        for (int r = 0; r < 8; ++r) {
            acc[r] += x[r * 128 + k + 0] * w.x + x[r * 128 + k + 1] * w.y
                    + x[r * 128 + k + 2] * w.z + x[r * 128 + k + 3] * w.w;
        }
    }
    const int h = t >> 4, d = t & 15;
    const float rs = paramR[h] * INV2PI;
    if (isQ) {
        float* dst = qs + row0 * 128 + t;
        #pragma unroll
        for (int r = 0; r < 8; ++r) dst[r * 128] = acc[r] * rs;
    } else {
        #pragma unroll
        for (int r = 0; r < 8; ++r) {
            const int row = row0 + r;
            const int j = row >> 2, b = row & 3;
            ksT[((d >> 2) * LK + j) * 128 + (b * 8 + h) * 4 + (d & 3)] = acc[r] * rs;
        }
    }
}

// ---------------------------------------------------------------------------
// Score: out[i][j][b][h] = | prod_d sin(2pi*u')/(2pi*u') |, u' = qs - ksT
// Computed as |prodN * rcp(prodD)| * (2pi)^-16, with per-d guard:
//   |u'|<=EPS -> (n,d) := (1, 1/(2pi))  => that factor contributes exactly 1.
// Thread: bh=t&31, js=t>>5. Block: 2 i's x 64 j's. k-loads 1KB/wave contiguous.
// ---------------------------------------------------------------------------
__global__ __launch_bounds__(256) void score_kernel(
    const float* __restrict__ qs, const float* __restrict__ ksT,
    float* __restrict__ out)
{
    const int t = threadIdx.x;
    const int bh = t & 31;
    const int js = t >> 5;                        // 0..7
    const int i0 = blockIdx.x * 2;                // 128 i-tiles
    const int jbase = blockIdx.y * 64;            // 8 j-tiles

    float q[2][16];
    #pragma unroll
    for (int ii = 0; ii < 2; ++ii) {
        const float* qp = qs + ((i0 + ii) * 32 + bh) * 16;
        #pragma unroll
        for (int d = 0; d < 16; d += 4) {
            const float4 v = *(const float4*)(qp + d);
            q[ii][d] = v.x; q[ii][d + 1] = v.y; q[ii][d + 2] = v.z; q[ii][d + 3] = v.w;
        }
    }

    constexpr float i2 = INV2PI * INV2PI;
    constexpr float i4 = i2 * i2;
    constexpr float i8 = i4 * i4;
    constexpr float C16 = i8 * i8;                // (2pi)^-16
    constexpr float EPS = 2.0e-4f * INV2PI;       // guard threshold in u' units

    float k[16];
    {
        const int j0 = jbase + js;
        #pragma unroll
        for (int d4 = 0; d4 < 4; ++d4) {
            const float4 v = *(const float4*)(ksT + (d4 * LK + j0) * 128 + bh * 4);
            k[d4 * 4 + 0] = v.x; k[d4 * 4 + 1] = v.y;
            k[d4 * 4 + 2] = v.z; k[d4 * 4 + 3] = v.w;
        }
    }

    #pragma unroll
    for (int m = 0; m < 8; ++m) {
        float kn[16];
        if (m < 7) {
            const int jn = jbase + (m + 1) * 8 + js;
            #pragma unroll
            for (int d4 = 0; d4 < 4; ++d4) {
                const float4 v = *(const float4*)(ksT + (d4 * LK + jn) * 128 + bh * 4);
                kn[d4 * 4 + 0] = v.x; kn[d4 * 4 + 1] = v.y;
                kn[d4 * 4 + 2] = v.z; kn[d4 * 4 + 3] = v.w;
            }
        }
        const int j = jbase + m * 8 + js;
        #pragma unroll
        for (int ii = 0; ii < 2; ++ii) {
            float pn0 = 1.f, pd0 = 1.f, pn1 = 1.f, pd1 = 1.f;
            #pragma unroll
            for (int d = 0; d < 16; ++d) {
                const float u = q[ii][d] - k[d];
                const float s = __builtin_amdgcn_sinf(u);   // sin(2pi*u)
                const bool g = __builtin_fabsf(u) > EPS;
                const float nn = g ? s : 1.0f;
                const float dd = g ? u : INV2PI;
                if (d < 8) { pn0 *= nn; pd0 *= dd; }
                else       { pn1 *= nn; pd1 *= dd; }
            }
            const float r0 = pn0 * __builtin_amdgcn_rcpf(pd0);
            const float r1 = pn1 * __builtin_amdgcn_rcpf(pd1);
            out[((i0 + ii) * LK + j) * 32 + bh] = __builtin_fabsf(r0 * r1) * C16;
        }
        if (m < 7) {
            #pragma unroll
            for (int d = 0; d < 16; ++d) k[d] = kn[d];
        }
    }
}

extern "C" void kernel_launch(void* const* d_in, const int* in_sizes, int n_in,
                              void* d_out, int out_size, void* d_ws, size_t ws_size,
                              hipStream_t stream) {
    const float* hh     = (const float*)d_in[0];
    const float* mems   = (const float*)d_in[1];
    const float* Wq     = (const float*)d_in[2];
    const float* Wk     = (const float*)d_in[3];
    const float* paramR = (const float*)d_in[4];
    float* out = (float*)d_out;

    float* qs  = (float*)d_ws;                // LQ*BB*128 = 131072 floats
    float* ksT = qs + LQ * BB * DM;           // 4*LK*128  = 262144 floats

    proj_kernel<<<384, 128, 0, stream>>>(hh, mems, Wq, Wk, paramR, qs, ksT);
    score_kernel<<<dim3(128, 8), 256, 0, stream>>>(qs, ksT, out);
}